// Round 1
// baseline (697.014 us; speedup 1.0000x reference)
//
#include <hip/hip_runtime.h>
#include <hip/hip_bf16.h>
#include <math.h>

#define N_EMBED 1024
#define N_HEAD 16
#define HD 64
#define BB 4
#define TT 2048
#define NTOK (BB * TT)        // 8192 rows
#define QKV_LD (3 * N_EMBED)  // 3072

typedef __bf16 bf16x8 __attribute__((ext_vector_type(8)));
typedef float f32x4 __attribute__((ext_vector_type(4)));

__device__ __forceinline__ unsigned short f2bf(float f) {
    __hip_bfloat16 h = __float2bfloat16(f);
    return __builtin_bit_cast(unsigned short, h);
}

// ---------------------------------------------------------------------------
// Weight transpose + fp32 -> bf16 convert:  in [K][N] fp32  ->  out [N][K] bf16
// ---------------------------------------------------------------------------
__global__ __launch_bounds__(256) void transpose_bf16_kernel(
    const float* __restrict__ in, unsigned short* __restrict__ out, int K, int N) {
    __shared__ float tile[32][33];
    int bx = blockIdx.x * 32;  // n base
    int by = blockIdx.y * 32;  // k base
    int tx = threadIdx.x, ty = threadIdx.y;
#pragma unroll
    for (int i = ty; i < 32; i += 8)
        tile[i][tx] = in[(size_t)(by + i) * N + bx + tx];
    __syncthreads();
#pragma unroll
    for (int i = ty; i < 32; i += 8)
        out[(size_t)(bx + i) * K + by + tx] = f2bf(tile[tx][i]);
}

// ---------------------------------------------------------------------------
// Row LayerNorm: fp32 in [rows][1024] -> bf16 out
// ---------------------------------------------------------------------------
__global__ __launch_bounds__(256) void ln_kernel(
    const float* __restrict__ x, const float* __restrict__ w,
    const float* __restrict__ b, unsigned short* __restrict__ out) {
    int row = blockIdx.x;
    int t = threadIdx.x;
    const float* xr = x + (size_t)row * N_EMBED;
    float4 v = reinterpret_cast<const float4*>(xr)[t];
    float s = v.x + v.y + v.z + v.w;
    float s2 = v.x * v.x + v.y * v.y + v.z * v.z + v.w * v.w;
#pragma unroll
    for (int m = 1; m < 64; m <<= 1) {
        s += __shfl_xor(s, m);
        s2 += __shfl_xor(s2, m);
    }
    __shared__ float red[8];
    int wv = t >> 6, ln = t & 63;
    if (ln == 0) { red[wv] = s; red[wv + 4] = s2; }
    __syncthreads();
    s = red[0] + red[1] + red[2] + red[3];
    s2 = red[4] + red[5] + red[6] + red[7];
    float mu = s * (1.0f / N_EMBED);
    float var = s2 * (1.0f / N_EMBED) - mu * mu;
    float r = rsqrtf(var + 1e-5f);
    float4 wv4 = reinterpret_cast<const float4*>(w)[t];
    float4 bv4 = reinterpret_cast<const float4*>(b)[t];
    ushort4 o;
    o.x = f2bf((v.x - mu) * r * wv4.x + bv4.x);
    o.y = f2bf((v.y - mu) * r * wv4.y + bv4.y);
    o.z = f2bf((v.z - mu) * r * wv4.z + bv4.z);
    o.w = f2bf((v.w - mu) * r * wv4.w + bv4.w);
    *reinterpret_cast<ushort4*>(out + (size_t)row * N_EMBED + t * 4) = o;
}

// ---------------------------------------------------------------------------
// bf16 GEMM: C[M][N] = A[M][K] @ BT[N][K]^T + bias, with epilogue variants.
// 128x128 block tile, 4 waves (2x2), each wave 64x64 (4x4 frags of 16x16x32).
// EPI 0: out bf16 = acc + bias
// EPI 1: out f32  = acc + bias + resid
// EPI 2: out bf16 = gelu(acc + bias)    (exact erf gelu)
// ---------------------------------------------------------------------------
template <int EPI>
__global__ __launch_bounds__(256) void gemm_kernel(
    const unsigned short* __restrict__ A,   // [M][K] bf16
    const unsigned short* __restrict__ BT,  // [N][K] bf16
    const float* __restrict__ bias,         // [N]
    const float* __restrict__ resid,        // [M][N] fp32 or nullptr
    float* __restrict__ outf,               // [M][N] fp32 (EPI 1)
    unsigned short* __restrict__ outb,      // [M][N] bf16 (EPI 0,2)
    int M, int N, int K) {
    __shared__ __align__(16) unsigned short As[128][40];
    __shared__ __align__(16) unsigned short Bs[128][40];
    int bm = blockIdx.y, bn = blockIdx.x;
    int t = threadIdx.x;
    int lane = t & 63, wv = t >> 6;
    int wm = wv >> 1, wn = wv & 1;
    int mr = lane & 15, kg = lane >> 4;

    f32x4 acc[4][4];
#pragma unroll
    for (int i = 0; i < 4; i++)
#pragma unroll
        for (int j = 0; j < 4; j++) acc[i][j] = (f32x4){0.f, 0.f, 0.f, 0.f};

    int srow = t >> 1, shalf = t & 1;
    const unsigned short* gA = A + (size_t)(bm * 128 + srow) * K + shalf * 16;
    const unsigned short* gB = BT + (size_t)(bn * 128 + srow) * K + shalf * 16;

    for (int k0 = 0; k0 < K; k0 += 32) {
        __syncthreads();
        uint4 a0 = *reinterpret_cast<const uint4*>(gA + k0);
        uint4 a1 = *reinterpret_cast<const uint4*>(gA + k0 + 8);
        uint4 b0 = *reinterpret_cast<const uint4*>(gB + k0);
        uint4 b1 = *reinterpret_cast<const uint4*>(gB + k0 + 8);
        *reinterpret_cast<uint4*>(&As[srow][shalf * 16]) = a0;
        *reinterpret_cast<uint4*>(&As[srow][shalf * 16 + 8]) = a1;
        *reinterpret_cast<uint4*>(&Bs[srow][shalf * 16]) = b0;
        *reinterpret_cast<uint4*>(&Bs[srow][shalf * 16 + 8]) = b1;
        __syncthreads();
        bf16x8 af[4], bfr[4];
#pragma unroll
        for (int i = 0; i < 4; i++)
            af[i] = *reinterpret_cast<const bf16x8*>(&As[wm * 64 + i * 16 + mr][kg * 8]);
#pragma unroll
        for (int j = 0; j < 4; j++)
            bfr[j] = *reinterpret_cast<const bf16x8*>(&Bs[wn * 64 + j * 16 + mr][kg * 8]);
#pragma unroll
        for (int i = 0; i < 4; i++)
#pragma unroll
            for (int j = 0; j < 4; j++)
                acc[i][j] = __builtin_amdgcn_mfma_f32_16x16x32_bf16(af[i], bfr[j], acc[i][j], 0, 0, 0);
    }

#pragma unroll
    for (int i = 0; i < 4; i++)
#pragma unroll
        for (int j = 0; j < 4; j++) {
            int n = bn * 128 + wn * 64 + j * 16 + mr;
            float bs = bias[n];
#pragma unroll
            for (int r = 0; r < 4; r++) {
                int m = bm * 128 + wm * 64 + i * 16 + kg * 4 + r;
                size_t idx = (size_t)m * N + n;
                float v = acc[i][j][r] + bs;
                if (EPI == 0) {
                    outb[idx] = f2bf(v);
                } else if (EPI == 1) {
                    outf[idx] = v + resid[idx];
                } else {
                    float g = 0.5f * v * (1.0f + erff(v * 0.70710678118f));
                    outb[idx] = f2bf(g);
                }
            }
        }
}

// ---------------------------------------------------------------------------
// Flash-style causal attention.
// qkv: [NTOK][3072] bf16 (q | k | v, each head h at offset h*64)
// ctx: [NTOK][1024] bf16 output
// One block per (b, h, q-tile of 64). 4 waves, each owns 16 q rows.
// ---------------------------------------------------------------------------
__global__ __launch_bounds__(256) void attn_kernel(
    const unsigned short* __restrict__ qkv, unsigned short* __restrict__ ctx) {
    const int QTILES = TT / 64;
    int bid = blockIdx.x;
    int qt = bid % QTILES;
    int bh = bid / QTILES;
    int h = bh % N_HEAD;
    int b = bh / N_HEAD;
    int t = threadIdx.x, lane = t & 63, wv = t >> 6;
    int mr = lane & 15, kg = lane >> 4;
    int qbase = qt * 64 + wv * 16;

    const unsigned short* qp = qkv + (size_t)(b * TT) * QKV_LD + h * HD;
    const unsigned short* kp = qp + N_EMBED;
    const unsigned short* vp = qp + 2 * N_EMBED;

    // Q fragments (A-operand): row = qbase+mr, dims c*32 + kg*8 ..+7
    bf16x8 aq[2];
#pragma unroll
    for (int c = 0; c < 2; c++)
        aq[c] = *reinterpret_cast<const bf16x8*>(
            qp + (size_t)(qbase + mr) * QKV_LD + c * 32 + kg * 8);

    __shared__ __align__(16) unsigned short VT[64][72];  // V^T: [d][kv]
    __shared__ __align__(16) unsigned short PL[64][72];  // P: [q_local][kv]

    f32x4 Oa[4];
#pragma unroll
    for (int jd = 0; jd < 4; jd++) Oa[jd] = (f32x4){0.f, 0.f, 0.f, 0.f};
    float mrow[4] = {-3.0e38f, -3.0e38f, -3.0e38f, -3.0e38f};
    float lrow[4] = {0.f, 0.f, 0.f, 0.f};

    int ntiles = qt + 1;
    for (int tile = 0; tile < ntiles; ++tile) {
        int kv0 = tile * 64;
        __syncthreads();
        // stage V^T tile into LDS (all 256 threads)
        {
            int r = t >> 2, q4 = t & 3;
            const unsigned short* src = vp + (size_t)(kv0 + r) * QKV_LD + q4 * 16;
            unsigned short tmp[16];
            *reinterpret_cast<uint4*>(tmp) = *reinterpret_cast<const uint4*>(src);
            *reinterpret_cast<uint4*>(tmp + 8) = *reinterpret_cast<const uint4*>(src + 8);
#pragma unroll
            for (int e = 0; e < 16; e++) VT[q4 * 16 + e][r] = tmp[e];
        }
        __syncthreads();

        // S = Q @ K^T for this wave's 16 q rows x 64 kv cols
        f32x4 sf[4];
#pragma unroll
        for (int j = 0; j < 4; j++) {
            f32x4 s = (f32x4){0.f, 0.f, 0.f, 0.f};
#pragma unroll
            for (int c = 0; c < 2; c++) {
                bf16x8 bk = *reinterpret_cast<const bf16x8*>(
                    kp + (size_t)(kv0 + j * 16 + mr) * QKV_LD + c * 32 + kg * 8);
                s = __builtin_amdgcn_mfma_f32_16x16x32_bf16(aq[c], bk, s, 0, 0, 0);
            }
            sf[j] = s;
        }

        // scale + causal mask + online softmax
        float tmax[4];
#pragma unroll
        for (int r = 0; r < 4; r++) {
            int qrow = qbase + kg * 4 + r;
            float mx = -3.0e38f;
#pragma unroll
            for (int j = 0; j < 4; j++) {
                int kc = kv0 + j * 16 + mr;
                float sv = sf[j][r] * 0.125f;
                if (kc > qrow) sv = -3.0e38f;
                sf[j][r] = sv;
                mx = fmaxf(mx, sv);
            }
#pragma unroll
            for (int m = 1; m < 16; m <<= 1) mx = fmaxf(mx, __shfl_xor(mx, m));
            tmax[r] = mx;
        }
        float alpha[4];
#pragma unroll
        for (int r = 0; r < 4; r++) {
            float mn = fmaxf(mrow[r], tmax[r]);
            alpha[r] = __expf(mrow[r] - mn);
            mrow[r] = mn;
        }
        float rsum[4] = {0.f, 0.f, 0.f, 0.f};
#pragma unroll
        for (int j = 0; j < 4; j++)
#pragma unroll
            for (int r = 0; r < 4; r++) {
                float p = __expf(sf[j][r] - mrow[r]);
                sf[j][r] = p;
                rsum[r] += p;
            }
#pragma unroll
        for (int r = 0; r < 4; r++) {
#pragma unroll
            for (int m = 1; m < 16; m <<= 1) rsum[r] += __shfl_xor(rsum[r], m);
            lrow[r] = lrow[r] * alpha[r] + rsum[r];
        }
#pragma unroll
        for (int jd = 0; jd < 4; jd++)
#pragma unroll
            for (int r = 0; r < 4; r++) Oa[jd][r] *= alpha[r];

        // write P to LDS (D-layout -> memory), re-read as A fragments
#pragma unroll
        for (int j = 0; j < 4; j++)
#pragma unroll
            for (int r = 0; r < 4; r++)
                PL[wv * 16 + kg * 4 + r][j * 16 + mr] = f2bf(sf[j][r]);
        __syncthreads();

        // O += P @ V
#pragma unroll
        for (int c = 0; c < 2; c++) {
            bf16x8 pa = *reinterpret_cast<const bf16x8*>(&PL[wv * 16 + mr][c * 32 + kg * 8]);
#pragma unroll
            for (int jd = 0; jd < 4; jd++) {
                bf16x8 vb = *reinterpret_cast<const bf16x8*>(&VT[jd * 16 + mr][c * 32 + kg * 8]);
                Oa[jd] = __builtin_amdgcn_mfma_f32_16x16x32_bf16(pa, vb, Oa[jd], 0, 0, 0);
            }
        }
    }

    // epilogue: ctx = O / l
#pragma unroll
    for (int jd = 0; jd < 4; jd++)
#pragma unroll
        for (int r = 0; r < 4; r++) {
            int q = qbase + kg * 4 + r;
            float v = Oa[jd][r] / lrow[r];
            ctx[(size_t)(b * TT + q) * N_EMBED + h * HD + jd * 16 + mr] = f2bf(v);
        }
}

// ---------------------------------------------------------------------------
extern "C" void kernel_launch(void* const* d_in, const int* in_sizes, int n_in,
                              void* d_out, int out_size, void* d_ws, size_t ws_size,
                              hipStream_t stream) {
    const float* x      = (const float*)d_in[0];
    const float* ln1_w  = (const float*)d_in[1];
    const float* ln1_b  = (const float*)d_in[2];
    const float* w_qkv  = (const float*)d_in[3];
    const float* b_qkv  = (const float*)d_in[4];
    const float* w_o    = (const float*)d_in[5];
    const float* b_o    = (const float*)d_in[6];
    const float* ln2_w  = (const float*)d_in[7];
    const float* ln2_b  = (const float*)d_in[8];
    const float* w_fc   = (const float*)d_in[9];
    const float* b_fc   = (const float*)d_in[10];
    const float* w_proj = (const float*)d_in[11];
    const float* b_proj = (const float*)d_in[12];
    float* out = (float*)d_out;

    char* ws = (char*)d_ws;
    size_t off = 0;
    auto alloc = [&](size_t bytes) -> void* {
        void* p = ws + off;
        off += (bytes + 255) & ~(size_t)255;
        return p;
    };
    unsigned short* wqkv_t  = (unsigned short*)alloc((size_t)3072 * 1024 * 2);
    unsigned short* wo_t    = (unsigned short*)alloc((size_t)1024 * 1024 * 2);
    unsigned short* wfc_t   = (unsigned short*)alloc((size_t)4096 * 1024 * 2);
    unsigned short* wproj_t = (unsigned short*)alloc((size_t)1024 * 4096 * 2);
    unsigned short* lnb     = (unsigned short*)alloc((size_t)NTOK * 1024 * 2);
    float*          x1      = (float*)alloc((size_t)NTOK * 1024 * 4);
    unsigned short* qkv     = (unsigned short*)alloc((size_t)NTOK * 3072 * 2);
    unsigned short* ctxb    = (unsigned short*)alloc((size_t)NTOK * 1024 * 2);
    unsigned short* hbuf    = qkv;  // [NTOK][4096] bf16 overlays qkv+ctx (both dead by then)

    dim3 tb32(32, 8);
    transpose_bf16_kernel<<<dim3(3072 / 32, 1024 / 32), tb32, 0, stream>>>(w_qkv, wqkv_t, 1024, 3072);
    transpose_bf16_kernel<<<dim3(1024 / 32, 1024 / 32), tb32, 0, stream>>>(w_o, wo_t, 1024, 1024);
    transpose_bf16_kernel<<<dim3(4096 / 32, 1024 / 32), tb32, 0, stream>>>(w_fc, wfc_t, 1024, 4096);
    transpose_bf16_kernel<<<dim3(1024 / 32, 4096 / 32), tb32, 0, stream>>>(w_proj, wproj_t, 4096, 1024);

    // ln1(x) -> lnb
    ln_kernel<<<NTOK, 256, 0, stream>>>(x, ln1_w, ln1_b, lnb);
    // qkv = lnb @ w_qkv + b_qkv
    gemm_kernel<0><<<dim3(3072 / 128, NTOK / 128), 256, 0, stream>>>(
        lnb, wqkv_t, b_qkv, nullptr, nullptr, qkv, NTOK, 3072, 1024);
    // attention -> ctx
    attn_kernel<<<BB * N_HEAD * (TT / 64), 256, 0, stream>>>(qkv, ctxb);
    // x1 = ctx @ w_o + b_o + x
    gemm_kernel<1><<<dim3(1024 / 128, NTOK / 128), 256, 0, stream>>>(
        ctxb, wo_t, b_o, x, x1, nullptr, NTOK, 1024, 1024);
    // ln2(x1) -> lnb
    ln_kernel<<<NTOK, 256, 0, stream>>>(x1, ln2_w, ln2_b, lnb);
    // h = gelu(lnb @ w_fc + b_fc)
    gemm_kernel<2><<<dim3(4096 / 128, NTOK / 128), 256, 0, stream>>>(
        lnb, wfc_t, b_fc, nullptr, nullptr, hbuf, NTOK, 4096, 1024);
    // out = h @ w_proj + b_proj + x1
    gemm_kernel<1><<<dim3(1024 / 128, NTOK / 128), 256, 0, stream>>>(
        hbuf, wproj_t, b_proj, x1, out, nullptr, NTOK, 1024, 4096);
}

// Round 2
// 609.684 us; speedup vs baseline: 1.1432x; 1.1432x over previous
//
#include <hip/hip_runtime.h>
#include <hip/hip_bf16.h>
#include <math.h>

#define N_EMBED 1024
#define N_HEAD 16
#define HD 64
#define BB 4
#define TT 2048
#define NTOK (BB * TT)        // 8192 rows
#define QKV_LD (3 * N_EMBED)  // 3072

typedef __bf16 bf16x8 __attribute__((ext_vector_type(8)));
typedef float f32x4 __attribute__((ext_vector_type(4)));

__device__ __forceinline__ unsigned short f2bf(float f) {
    __hip_bfloat16 h = __float2bfloat16(f);
    return __builtin_bit_cast(unsigned short, h);
}

// async global->LDS, 16B per lane. LDS dest = wave-uniform base + lane*16.
__device__ __forceinline__ void gll16(const unsigned short* g, unsigned short* l) {
    __builtin_amdgcn_global_load_lds(
        (const __attribute__((address_space(1))) void*)g,
        (__attribute__((address_space(3))) void*)l,
        16, 0, 0);
}

// ---------------------------------------------------------------------------
// Weight transpose + fp32 -> bf16 convert:  in [K][N] fp32  ->  out [N][K] bf16
// ---------------------------------------------------------------------------
__global__ __launch_bounds__(256) void transpose_bf16_kernel(
    const float* __restrict__ in, unsigned short* __restrict__ out, int K, int N) {
    __shared__ float tile[32][33];
    int bx = blockIdx.x * 32;  // n base
    int by = blockIdx.y * 32;  // k base
    int tx = threadIdx.x, ty = threadIdx.y;
#pragma unroll
    for (int i = ty; i < 32; i += 8)
        tile[i][tx] = in[(size_t)(by + i) * N + bx + tx];
    __syncthreads();
#pragma unroll
    for (int i = ty; i < 32; i += 8)
        out[(size_t)(bx + i) * K + by + tx] = f2bf(tile[tx][i]);
}

// ---------------------------------------------------------------------------
// V transpose: qkv [B*T][3072] (v at col 2048+h*64) -> vt [b*16+h][64][2048]
// ---------------------------------------------------------------------------
__global__ __launch_bounds__(256) void transpose_v_kernel(
    const unsigned short* __restrict__ qkv, unsigned short* __restrict__ vt) {
    __shared__ unsigned short tile[32][33];
    int z = blockIdx.z;
    int b = z >> 4, h = z & 15;
    int t0 = blockIdx.x * 32, d0 = blockIdx.y * 32;
    int tx = threadIdx.x, ty = threadIdx.y;
    const unsigned short* src = qkv + (size_t)(b * TT) * QKV_LD + 2 * N_EMBED + h * HD;
#pragma unroll
    for (int i = ty; i < 32; i += 8)
        tile[i][tx] = src[(size_t)(t0 + i) * QKV_LD + d0 + tx];
    __syncthreads();
    unsigned short* dst = vt + (size_t)z * HD * TT;
#pragma unroll
    for (int i = ty; i < 32; i += 8)
        dst[(size_t)(d0 + i) * TT + t0 + tx] = tile[tx][i];
}

// ---------------------------------------------------------------------------
// Row LayerNorm: fp32 in [rows][1024] -> bf16 out
// ---------------------------------------------------------------------------
__global__ __launch_bounds__(256) void ln_kernel(
    const float* __restrict__ x, const float* __restrict__ w,
    const float* __restrict__ b, unsigned short* __restrict__ out) {
    int row = blockIdx.x;
    int t = threadIdx.x;
    const float* xr = x + (size_t)row * N_EMBED;
    float4 v = reinterpret_cast<const float4*>(xr)[t];
    float s = v.x + v.y + v.z + v.w;
    float s2 = v.x * v.x + v.y * v.y + v.z * v.z + v.w * v.w;
#pragma unroll
    for (int m = 1; m < 64; m <<= 1) {
        s += __shfl_xor(s, m);
        s2 += __shfl_xor(s2, m);
    }
    __shared__ float red[8];
    int wv = t >> 6, ln = t & 63;
    if (ln == 0) { red[wv] = s; red[wv + 4] = s2; }
    __syncthreads();
    s = red[0] + red[1] + red[2] + red[3];
    s2 = red[4] + red[5] + red[6] + red[7];
    float mu = s * (1.0f / N_EMBED);
    float var = s2 * (1.0f / N_EMBED) - mu * mu;
    float r = rsqrtf(var + 1e-5f);
    float4 wv4 = reinterpret_cast<const float4*>(w)[t];
    float4 bv4 = reinterpret_cast<const float4*>(b)[t];
    ushort4 o;
    o.x = f2bf((v.x - mu) * r * wv4.x + bv4.x);
    o.y = f2bf((v.y - mu) * r * wv4.y + bv4.y);
    o.z = f2bf((v.z - mu) * r * wv4.z + bv4.z);
    o.w = f2bf((v.w - mu) * r * wv4.w + bv4.w);
    *reinterpret_cast<ushort4*>(out + (size_t)row * N_EMBED + t * 4) = o;
}

// ---------------------------------------------------------------------------
// bf16 GEMM: C[M][N] = A[M][K] @ BT[N][K]^T + bias. m97 structure:
// 128x128 tile, BK=32, linear LDS [128][32], global_load_lds width-16 staging.
// EPI 0: out bf16 = acc + bias
// EPI 1: out f32  = acc + bias + resid
// EPI 2: out bf16 = gelu(acc + bias)
// ---------------------------------------------------------------------------
template <int EPI>
__global__ __launch_bounds__(256) void gemm_kernel(
    const unsigned short* __restrict__ A,   // [M][K] bf16
    const unsigned short* __restrict__ BT,  // [N][K] bf16
    const float* __restrict__ bias,         // [N]
    const float* __restrict__ resid,        // [M][N] fp32 or nullptr
    float* __restrict__ outf,               // [M][N] fp32 (EPI 1)
    unsigned short* __restrict__ outb,      // [M][N] bf16 (EPI 0,2)
    int M, int N, int K) {
    __shared__ __align__(16) unsigned short As[128 * 32];
    __shared__ __align__(16) unsigned short Bs[128 * 32];
    int bm = blockIdx.y, bn = blockIdx.x;
    int t = threadIdx.x;
    int lane = t & 63, wv = t >> 6;
    int wm = wv >> 1, wn = wv & 1;
    int mr = lane & 15, kg = lane >> 4;

    f32x4 acc[4][4];
#pragma unroll
    for (int i = 0; i < 4; i++)
#pragma unroll
        for (int j = 0; j < 4; j++) acc[i][j] = (f32x4){0.f, 0.f, 0.f, 0.f};

    // staging: chunk c (16B) -> row c>>2, k-quarter c&3; thread t owns chunks t, t+256
    int srow = t >> 2, sq = t & 3;
    const unsigned short* gA1 = A + (size_t)(bm * 128 + srow) * K + sq * 8;
    const unsigned short* gA2 = gA1 + (size_t)64 * K;
    const unsigned short* gB1 = BT + (size_t)(bn * 128 + srow) * K + sq * 8;
    const unsigned short* gB2 = gB1 + (size_t)64 * K;
    int w512 = (t >> 6) * 512;  // wave-uniform LDS base (ushorts)

    for (int k0 = 0; k0 < K; k0 += 32) {
        __syncthreads();
        gll16(gA1 + k0, As + w512);
        gll16(gA2 + k0, As + 2048 + w512);
        gll16(gB1 + k0, Bs + w512);
        gll16(gB2 + k0, Bs + 2048 + w512);
        __syncthreads();
        bf16x8 af[4], bfr[4];
#pragma unroll
        for (int i = 0; i < 4; i++)
            af[i] = *reinterpret_cast<const bf16x8*>(&As[(wm * 64 + i * 16 + mr) * 32 + kg * 8]);
#pragma unroll
        for (int j = 0; j < 4; j++)
            bfr[j] = *reinterpret_cast<const bf16x8*>(&Bs[(wn * 64 + j * 16 + mr) * 32 + kg * 8]);
#pragma unroll
        for (int i = 0; i < 4; i++)
#pragma unroll
            for (int j = 0; j < 4; j++)
                acc[i][j] = __builtin_amdgcn_mfma_f32_16x16x32_bf16(af[i], bfr[j], acc[i][j], 0, 0, 0);
    }

#pragma unroll
    for (int i = 0; i < 4; i++)
#pragma unroll
        for (int j = 0; j < 4; j++) {
            int n = bn * 128 + wn * 64 + j * 16 + mr;
            float bs = bias[n];
#pragma unroll
            for (int r = 0; r < 4; r++) {
                int m = bm * 128 + wm * 64 + i * 16 + kg * 4 + r;
                size_t idx = (size_t)m * N + n;
                float v = acc[i][j][r] + bs;
                if (EPI == 0) {
                    outb[idx] = f2bf(v);
                } else if (EPI == 1) {
                    outf[idx] = v + resid[idx];
                } else {
                    float g = 0.5f * v * (1.0f + erff(v * 0.70710678118f));
                    outb[idx] = f2bf(g);
                }
            }
        }
}

// ---------------------------------------------------------------------------
// Flash-style causal attention, barrier-free, LPT-paired work items.
// 1024 blocks; block b handles items {b, 2047-b}; tiles(item)=(wid>>6)+1 so
// every block does exactly 33 KV-tile iterations.
// qkv: [NTOK][3072] bf16; vt: [b*16+h][64][2048] bf16 (V pre-transposed);
// ctx: [NTOK][1024] bf16.
// ---------------------------------------------------------------------------
__global__ __launch_bounds__(256) void attn_kernel(
    const unsigned short* __restrict__ qkv,
    const unsigned short* __restrict__ vt,
    unsigned short* __restrict__ ctx) {
    __shared__ __align__(16) unsigned short PL[64][72];  // wave-local P bounce
    int t = threadIdx.x, lane = t & 63, wv = t >> 6;
    int mr = lane & 15, kg = lane >> 4;

#pragma unroll
    for (int item = 0; item < 2; ++item) {
        int wid = (item == 0) ? (int)blockIdx.x : (2047 - (int)blockIdx.x);
        int qt = wid >> 6;  // 0..31
        int bh = wid & 63;
        int h = bh & 15, b = bh >> 4;
        int qbase = qt * 64 + wv * 16;

        const unsigned short* qp = qkv + (size_t)(b * TT) * QKV_LD + h * HD;
        const unsigned short* kp = qp + N_EMBED;
        const unsigned short* vtp = vt + (size_t)bh * HD * TT;

        bf16x8 aq[2];
#pragma unroll
        for (int c = 0; c < 2; c++)
            aq[c] = *reinterpret_cast<const bf16x8*>(
                qp + (size_t)(qbase + mr) * QKV_LD + c * 32 + kg * 8);

        f32x4 Oa[4];
#pragma unroll
        for (int jd = 0; jd < 4; jd++) Oa[jd] = (f32x4){0.f, 0.f, 0.f, 0.f};
        float mrow[4] = {-3.0e38f, -3.0e38f, -3.0e38f, -3.0e38f};
        float lrow[4] = {0.f, 0.f, 0.f, 0.f};

        for (int tile = 0; tile <= qt; ++tile) {
            int kv0 = tile * 64;

            // S = Q @ K^T  (16 q rows x 64 kv cols per wave)
            f32x4 sf[4];
#pragma unroll
            for (int j = 0; j < 4; j++) {
                f32x4 s = (f32x4){0.f, 0.f, 0.f, 0.f};
#pragma unroll
                for (int c = 0; c < 2; c++) {
                    bf16x8 bk = *reinterpret_cast<const bf16x8*>(
                        kp + (size_t)(kv0 + j * 16 + mr) * QKV_LD + c * 32 + kg * 8);
                    s = __builtin_amdgcn_mfma_f32_16x16x32_bf16(aq[c], bk, s, 0, 0, 0);
                }
                sf[j] = s;
            }

            // scale + causal mask + online softmax
            float tmax[4];
#pragma unroll
            for (int r = 0; r < 4; r++) {
                int qrow = qbase + kg * 4 + r;
                float mx = -3.0e38f;
#pragma unroll
                for (int j = 0; j < 4; j++) {
                    int kc = kv0 + j * 16 + mr;
                    float sv = sf[j][r] * 0.125f;
                    if (kc > qrow) sv = -3.0e38f;
                    sf[j][r] = sv;
                    mx = fmaxf(mx, sv);
                }
#pragma unroll
                for (int m = 1; m < 16; m <<= 1) mx = fmaxf(mx, __shfl_xor(mx, m));
                tmax[r] = mx;
            }
            float alpha[4];
#pragma unroll
            for (int r = 0; r < 4; r++) {
                float mn = fmaxf(mrow[r], tmax[r]);
                alpha[r] = __expf(mrow[r] - mn);
                mrow[r] = mn;
            }
            float rsum[4] = {0.f, 0.f, 0.f, 0.f};
#pragma unroll
            for (int j = 0; j < 4; j++)
#pragma unroll
                for (int r = 0; r < 4; r++) {
                    float p = __expf(sf[j][r] - mrow[r]);
                    sf[j][r] = p;
                    rsum[r] += p;
                }
#pragma unroll
            for (int r = 0; r < 4; r++) {
#pragma unroll
                for (int m = 1; m < 16; m <<= 1) rsum[r] += __shfl_xor(rsum[r], m);
                lrow[r] = lrow[r] * alpha[r] + rsum[r];
            }
#pragma unroll
            for (int jd = 0; jd < 4; jd++)
#pragma unroll
                for (int r = 0; r < 4; r++) Oa[jd][r] *= alpha[r];

            // P -> LDS (wave-local: rows wv*16..wv*16+15 only) -> A fragments
#pragma unroll
            for (int j = 0; j < 4; j++)
#pragma unroll
                for (int r = 0; r < 4; r++)
                    PL[wv * 16 + kg * 4 + r][j * 16 + mr] = f2bf(sf[j][r]);
            __builtin_amdgcn_sched_barrier(0);  // keep ds_reads after ds_writes

            // O += P @ V   (V^T fragments straight from global, vectorized)
#pragma unroll
            for (int c = 0; c < 2; c++) {
                bf16x8 pa = *reinterpret_cast<const bf16x8*>(&PL[wv * 16 + mr][c * 32 + kg * 8]);
#pragma unroll
                for (int jd = 0; jd < 4; jd++) {
                    bf16x8 vb = *reinterpret_cast<const bf16x8*>(
                        vtp + (size_t)(jd * 16 + mr) * TT + kv0 + c * 32 + kg * 8);
                    Oa[jd] = __builtin_amdgcn_mfma_f32_16x16x32_bf16(pa, vb, Oa[jd], 0, 0, 0);
                }
            }
        }

        // epilogue: ctx = O / l
        float inv[4];
#pragma unroll
        for (int r = 0; r < 4; r++) inv[r] = 1.0f / lrow[r];
#pragma unroll
        for (int jd = 0; jd < 4; jd++)
#pragma unroll
            for (int r = 0; r < 4; r++) {
                int q = qbase + kg * 4 + r;
                ctx[(size_t)(b * TT + q) * N_EMBED + h * HD + jd * 16 + mr] =
                    f2bf(Oa[jd][r] * inv[r]);
            }
    }
}

// ---------------------------------------------------------------------------
extern "C" void kernel_launch(void* const* d_in, const int* in_sizes, int n_in,
                              void* d_out, int out_size, void* d_ws, size_t ws_size,
                              hipStream_t stream) {
    const float* x      = (const float*)d_in[0];
    const float* ln1_w  = (const float*)d_in[1];
    const float* ln1_b  = (const float*)d_in[2];
    const float* w_qkv  = (const float*)d_in[3];
    const float* b_qkv  = (const float*)d_in[4];
    const float* w_o    = (const float*)d_in[5];
    const float* b_o    = (const float*)d_in[6];
    const float* ln2_w  = (const float*)d_in[7];
    const float* ln2_b  = (const float*)d_in[8];
    const float* w_fc   = (const float*)d_in[9];
    const float* b_fc   = (const float*)d_in[10];
    const float* w_proj = (const float*)d_in[11];
    const float* b_proj = (const float*)d_in[12];
    float* out = (float*)d_out;

    char* ws = (char*)d_ws;
    size_t off = 0;
    auto alloc = [&](size_t bytes) -> void* {
        void* p = ws + off;
        off += (bytes + 255) & ~(size_t)255;
        return p;
    };
    unsigned short* wqkv_t  = (unsigned short*)alloc((size_t)3072 * 1024 * 2);
    unsigned short* wo_t    = (unsigned short*)alloc((size_t)1024 * 1024 * 2);
    unsigned short* wfc_t   = (unsigned short*)alloc((size_t)4096 * 1024 * 2);
    unsigned short* wproj_t = (unsigned short*)alloc((size_t)1024 * 4096 * 2);
    unsigned short* lnb     = (unsigned short*)alloc((size_t)NTOK * 1024 * 2);
    float*          x1      = (float*)alloc((size_t)NTOK * 1024 * 4);
    unsigned short* qkv     = (unsigned short*)alloc((size_t)NTOK * 3072 * 2);
    unsigned short* ctxb    = (unsigned short*)alloc((size_t)NTOK * 1024 * 2);
    unsigned short* hbuf    = qkv;                 // overlays qkv (dead after attn)
    unsigned short* vt      = (unsigned short*)x1; // overlays x1 (written after attn)

    dim3 tb32(32, 8);
    transpose_bf16_kernel<<<dim3(3072 / 32, 1024 / 32), tb32, 0, stream>>>(w_qkv, wqkv_t, 1024, 3072);
    transpose_bf16_kernel<<<dim3(1024 / 32, 1024 / 32), tb32, 0, stream>>>(w_o, wo_t, 1024, 1024);
    transpose_bf16_kernel<<<dim3(4096 / 32, 1024 / 32), tb32, 0, stream>>>(w_fc, wfc_t, 1024, 4096);
    transpose_bf16_kernel<<<dim3(1024 / 32, 4096 / 32), tb32, 0, stream>>>(w_proj, wproj_t, 4096, 1024);

    // ln1(x) -> lnb
    ln_kernel<<<NTOK, 256, 0, stream>>>(x, ln1_w, ln1_b, lnb);
    // qkv = lnb @ w_qkv + b_qkv
    gemm_kernel<0><<<dim3(3072 / 128, NTOK / 128), 256, 0, stream>>>(
        lnb, wqkv_t, b_qkv, nullptr, nullptr, qkv, NTOK, 3072, 1024);
    // V transpose -> vt
    transpose_v_kernel<<<dim3(TT / 32, HD / 32, BB * N_HEAD), tb32, 0, stream>>>(qkv, vt);
    // attention -> ctx
    attn_kernel<<<1024, 256, 0, stream>>>(qkv, vt, ctxb);
    // x1 = ctx @ w_o + b_o + x   (x1 overwrites vt region — vt dead now)
    gemm_kernel<1><<<dim3(1024 / 128, NTOK / 128), 256, 0, stream>>>(
        ctxb, wo_t, b_o, x, x1, nullptr, NTOK, 1024, 1024);
    // ln2(x1) -> lnb
    ln_kernel<<<NTOK, 256, 0, stream>>>(x1, ln2_w, ln2_b, lnb);
    // h = gelu(lnb @ w_fc + b_fc)
    gemm_kernel<2><<<dim3(4096 / 128, NTOK / 128), 256, 0, stream>>>(
        lnb, wfc_t, b_fc, nullptr, nullptr, hbuf, NTOK, 4096, 1024);
    // out = h @ w_proj + b_proj + x1
    gemm_kernel<1><<<dim3(1024 / 128, NTOK / 128), 256, 0, stream>>>(
        hbuf, wproj_t, b_proj, x1, out, nullptr, NTOK, 1024, 4096);
}

// Round 3
// 469.383 us; speedup vs baseline: 1.4850x; 1.2989x over previous
//
#include <hip/hip_runtime.h>
#include <hip/hip_bf16.h>
#include <math.h>

#define N_EMBED 1024
#define N_HEAD 16
#define HD 64
#define BB 4
#define TT 2048
#define NTOK (BB * TT)        // 8192 rows
#define QKV_LD (3 * N_EMBED)  // 3072

typedef __bf16 bf16x8 __attribute__((ext_vector_type(8)));
typedef float f32x4 __attribute__((ext_vector_type(4)));

__device__ __forceinline__ unsigned short f2bf(float f) {
    __hip_bfloat16 h = __float2bfloat16(f);
    return __builtin_bit_cast(unsigned short, h);
}

// async global->LDS, 16B per lane. LDS dest = wave-uniform base + lane*16.
__device__ __forceinline__ void gll16(const unsigned short* g, unsigned short* l) {
    __builtin_amdgcn_global_load_lds(
        (const __attribute__((address_space(1))) void*)g,
        (__attribute__((address_space(3))) void*)l,
        16, 0, 0);
}

// ---------------------------------------------------------------------------
// Weight transpose + fp32 -> bf16 convert:  in [K][N] fp32  ->  out [N][K] bf16
// ---------------------------------------------------------------------------
__global__ __launch_bounds__(256) void transpose_bf16_kernel(
    const float* __restrict__ in, unsigned short* __restrict__ out, int K, int N) {
    __shared__ float tile[32][33];
    int bx = blockIdx.x * 32;  // n base
    int by = blockIdx.y * 32;  // k base
    int tx = threadIdx.x, ty = threadIdx.y;
#pragma unroll
    for (int i = ty; i < 32; i += 8)
        tile[i][tx] = in[(size_t)(by + i) * N + bx + tx];
    __syncthreads();
#pragma unroll
    for (int i = ty; i < 32; i += 8)
        out[(size_t)(bx + i) * K + by + tx] = f2bf(tile[tx][i]);
}

// ---------------------------------------------------------------------------
// V transpose: qkv [B*T][3072] (v at col 2048+h*64) -> vt [b*16+h][64][2048]
// ---------------------------------------------------------------------------
__global__ __launch_bounds__(256) void transpose_v_kernel(
    const unsigned short* __restrict__ qkv, unsigned short* __restrict__ vt) {
    __shared__ unsigned short tile[32][33];
    int z = blockIdx.z;
    int b = z >> 4, h = z & 15;
    int t0 = blockIdx.x * 32, d0 = blockIdx.y * 32;
    int tx = threadIdx.x, ty = threadIdx.y;
    const unsigned short* src = qkv + (size_t)(b * TT) * QKV_LD + 2 * N_EMBED + h * HD;
#pragma unroll
    for (int i = ty; i < 32; i += 8)
        tile[i][tx] = src[(size_t)(t0 + i) * QKV_LD + d0 + tx];
    __syncthreads();
    unsigned short* dst = vt + (size_t)z * HD * TT;
#pragma unroll
    for (int i = ty; i < 32; i += 8)
        dst[(size_t)(d0 + i) * TT + t0 + tx] = tile[tx][i];
}

// ---------------------------------------------------------------------------
// Row LayerNorm: fp32 in [rows][1024] -> bf16 out
// ---------------------------------------------------------------------------
__global__ __launch_bounds__(256) void ln_kernel(
    const float* __restrict__ x, const float* __restrict__ w,
    const float* __restrict__ b, unsigned short* __restrict__ out) {
    int row = blockIdx.x;
    int t = threadIdx.x;
    const float* xr = x + (size_t)row * N_EMBED;
    float4 v = reinterpret_cast<const float4*>(xr)[t];
    float s = v.x + v.y + v.z + v.w;
    float s2 = v.x * v.x + v.y * v.y + v.z * v.z + v.w * v.w;
#pragma unroll
    for (int m = 1; m < 64; m <<= 1) {
        s += __shfl_xor(s, m);
        s2 += __shfl_xor(s2, m);
    }
    __shared__ float red[8];
    int wv = t >> 6, ln = t & 63;
    if (ln == 0) { red[wv] = s; red[wv + 4] = s2; }
    __syncthreads();
    s = red[0] + red[1] + red[2] + red[3];
    s2 = red[4] + red[5] + red[6] + red[7];
    float mu = s * (1.0f / N_EMBED);
    float var = s2 * (1.0f / N_EMBED) - mu * mu;
    float r = rsqrtf(var + 1e-5f);
    float4 wv4 = reinterpret_cast<const float4*>(w)[t];
    float4 bv4 = reinterpret_cast<const float4*>(b)[t];
    ushort4 o;
    o.x = f2bf((v.x - mu) * r * wv4.x + bv4.x);
    o.y = f2bf((v.y - mu) * r * wv4.y + bv4.y);
    o.z = f2bf((v.z - mu) * r * wv4.z + bv4.z);
    o.w = f2bf((v.w - mu) * r * wv4.w + bv4.w);
    *reinterpret_cast<ushort4*>(out + (size_t)row * N_EMBED + t * 4) = o;
}

// ---------------------------------------------------------------------------
// bf16 GEMM: C[M][N] = A[M][K] @ BT[N][K]^T + bias. m97 structure + XCD swizzle.
// 128x128 tile, BK=32, linear LDS, global_load_lds width-16 staging.
// grid is FLAT: nwg = (M/128)*(N/128), must be divisible by 8.
// EPI 0: out bf16 = acc + bias
// EPI 1: out f32  = acc + bias + resid
// EPI 2: out bf16 = gelu(acc + bias)
// ---------------------------------------------------------------------------
template <int EPI>
__global__ __launch_bounds__(256) void gemm_kernel(
    const unsigned short* __restrict__ A,   // [M][K] bf16
    const unsigned short* __restrict__ BT,  // [N][K] bf16
    const float* __restrict__ bias,         // [N]
    const float* __restrict__ resid,        // [M][N] fp32 or nullptr
    float* __restrict__ outf,               // [M][N] fp32 (EPI 1)
    unsigned short* __restrict__ outb,      // [M][N] bf16 (EPI 0,2)
    int M, int N, int K) {
    __shared__ __align__(16) unsigned short As[128 * 32];
    __shared__ __align__(16) unsigned short Bs[128 * 32];
    // bijective XCD swizzle (nwg % 8 == 0): XCD x gets a contiguous bm band
    int nbn = N >> 7;
    int nwg = gridDim.x;
    int orig = blockIdx.x;
    int swz = (orig & 7) * (nwg >> 3) + (orig >> 3);
    int bm = swz / nbn, bn = swz % nbn;
    int t = threadIdx.x;
    int lane = t & 63, wv = t >> 6;
    int wm = wv >> 1, wn = wv & 1;
    int mr = lane & 15, kg = lane >> 4;

    f32x4 acc[4][4];
#pragma unroll
    for (int i = 0; i < 4; i++)
#pragma unroll
        for (int j = 0; j < 4; j++) acc[i][j] = (f32x4){0.f, 0.f, 0.f, 0.f};

    // staging: chunk c (16B) -> row c>>2, k-quarter c&3; thread t owns chunks t, t+256
    int srow = t >> 2, sq = t & 3;
    const unsigned short* gA1 = A + (size_t)(bm * 128 + srow) * K + sq * 8;
    const unsigned short* gA2 = gA1 + (size_t)64 * K;
    const unsigned short* gB1 = BT + (size_t)(bn * 128 + srow) * K + sq * 8;
    const unsigned short* gB2 = gB1 + (size_t)64 * K;
    int w512 = (t >> 6) * 512;  // wave-uniform LDS base (ushorts)

    for (int k0 = 0; k0 < K; k0 += 32) {
        __syncthreads();
        gll16(gA1 + k0, As + w512);
        gll16(gA2 + k0, As + 2048 + w512);
        gll16(gB1 + k0, Bs + w512);
        gll16(gB2 + k0, Bs + 2048 + w512);
        __syncthreads();
        bf16x8 af[4], bfr[4];
#pragma unroll
        for (int i = 0; i < 4; i++)
            af[i] = *reinterpret_cast<const bf16x8*>(&As[(wm * 64 + i * 16 + mr) * 32 + kg * 8]);
#pragma unroll
        for (int j = 0; j < 4; j++)
            bfr[j] = *reinterpret_cast<const bf16x8*>(&Bs[(wn * 64 + j * 16 + mr) * 32 + kg * 8]);
#pragma unroll
        for (int i = 0; i < 4; i++)
#pragma unroll
            for (int j = 0; j < 4; j++)
                acc[i][j] = __builtin_amdgcn_mfma_f32_16x16x32_bf16(af[i], bfr[j], acc[i][j], 0, 0, 0);
    }

#pragma unroll
    for (int i = 0; i < 4; i++)
#pragma unroll
        for (int j = 0; j < 4; j++) {
            int n = bn * 128 + wn * 64 + j * 16 + mr;
            float bs = bias[n];
#pragma unroll
            for (int r = 0; r < 4; r++) {
                int m = bm * 128 + wm * 64 + i * 16 + kg * 4 + r;
                size_t idx = (size_t)m * N + n;
                float v = acc[i][j][r] + bs;
                if (EPI == 0) {
                    outb[idx] = f2bf(v);
                } else if (EPI == 1) {
                    outf[idx] = v + resid[idx];
                } else {
                    float g = 0.5f * v * (1.0f + erff(v * 0.70710678118f));
                    outb[idx] = f2bf(g);
                }
            }
        }
}

// ---------------------------------------------------------------------------
// Flash-style causal attention, LDS-staged K/V (double-buffered, source-side
// XOR swizzle), LPT-paired work items, one barrier per KV tile.
// 1024 blocks; block b handles items {b, 2047-b} -> exactly 33 tiles/block.
// qkv: [NTOK][3072] bf16; vt: [b*16+h][64][2048] bf16; ctx: [NTOK][1024] bf16.
// LDS: K dbuf 16KB + V dbuf 16KB + P bounce 8KB = 40KB -> 4 blocks/CU.
// ---------------------------------------------------------------------------
__global__ __launch_bounds__(256, 4) void attn_kernel(
    const unsigned short* __restrict__ qkv,
    const unsigned short* __restrict__ vt,
    unsigned short* __restrict__ ctx) {
    __shared__ __align__(16) unsigned short Kb[2][4096];
    __shared__ __align__(16) unsigned short Vb[2][4096];
    __shared__ __align__(16) unsigned short PL[4096];
    int t = threadIdx.x, lane = t & 63, wv = t >> 6;
    int mr = lane & 15, kg = lane >> 4;
    const float SCL = 0.18033688011112042f;  // 0.125 * log2(e)

    // staging geometry (loop-invariant): call i covers chunks i*256 + wv*64 + lane
    int srow[2], scol[2], sbase[2];
#pragma unroll
    for (int i = 0; i < 2; i++) {
        int L = i * 256 + wv * 64 + lane;
        int row = L >> 3, slot = L & 7;
        srow[i] = row;
        scol[i] = (slot ^ (row & 7)) * 8;       // pre-swizzled global chunk
        sbase[i] = (i * 256 + wv * 64) * 8;     // wave-uniform LDS base (ushorts)
    }
    const int csw = mr & 7;  // read-side chunk XOR (row&7 with row = *16 + mr)

#pragma unroll
    for (int item = 0; item < 2; ++item) {
        int wid = (item == 0) ? (int)blockIdx.x : (2047 - (int)blockIdx.x);
        int qt = wid >> 6;  // 0..31
        int bh = wid & 63;
        int h = bh & 15, b = bh >> 4;
        int qbase = qt * 64 + wv * 16;

        const unsigned short* qp = qkv + (size_t)(b * TT) * QKV_LD + h * HD;
        const unsigned short* kp = qp + N_EMBED;
        const unsigned short* vtp = vt + (size_t)bh * HD * TT;

        bf16x8 aq[2];
#pragma unroll
        for (int c = 0; c < 2; c++)
            aq[c] = *reinterpret_cast<const bf16x8*>(
                qp + (size_t)(qbase + mr) * QKV_LD + c * 32 + kg * 8);

        f32x4 Oa[4];
#pragma unroll
        for (int jd = 0; jd < 4; jd++) Oa[jd] = (f32x4){0.f, 0.f, 0.f, 0.f};
        float mrow[4] = {-3.0e38f, -3.0e38f, -3.0e38f, -3.0e38f};
        float lrow[4] = {0.f, 0.f, 0.f, 0.f};

        // prologue: stage tile 0 into buf 0
#pragma unroll
        for (int i = 0; i < 2; i++) {
            gll16(kp + (size_t)srow[i] * QKV_LD + scol[i], &Kb[0][sbase[i]]);
            gll16(vtp + (size_t)srow[i] * TT + scol[i], &Vb[0][sbase[i]]);
        }
        __syncthreads();

        for (int tile = 0; tile <= qt; ++tile) {
            int cur = tile & 1;
            int kv0 = tile * 64;
            if (tile < qt) {
                int nkv = kv0 + 64;
#pragma unroll
                for (int i = 0; i < 2; i++) {
                    gll16(kp + (size_t)(nkv + srow[i]) * QKV_LD + scol[i], &Kb[cur ^ 1][sbase[i]]);
                    gll16(vtp + (size_t)srow[i] * TT + nkv + scol[i], &Vb[cur ^ 1][sbase[i]]);
                }
            }

            // S = Q @ K^T  (16 q rows x 64 kv cols per wave)
            f32x4 sf[4];
#pragma unroll
            for (int j = 0; j < 4; j++) {
                int rl = j * 16 + mr;
                f32x4 s = (f32x4){0.f, 0.f, 0.f, 0.f};
#pragma unroll
                for (int c = 0; c < 2; c++) {
                    bf16x8 bk = *reinterpret_cast<const bf16x8*>(
                        &Kb[cur][rl * 64 + ((4 * c + kg) ^ csw) * 8]);
                    s = __builtin_amdgcn_mfma_f32_16x16x32_bf16(aq[c], bk, s, 0, 0, 0);
                }
                sf[j] = s;
            }

            // scale (log2 domain) + causal mask (diagonal tile only) + online softmax
            float tmax[4];
            if (tile == qt) {
#pragma unroll
                for (int r = 0; r < 4; r++) {
                    int qrow = qbase + kg * 4 + r;
                    float mx = -3.0e38f;
#pragma unroll
                    for (int j = 0; j < 4; j++) {
                        int kc = kv0 + j * 16 + mr;
                        float sv = sf[j][r] * SCL;
                        if (kc > qrow) sv = -3.0e38f;
                        sf[j][r] = sv;
                        mx = fmaxf(mx, sv);
                    }
                    tmax[r] = mx;
                }
            } else {
#pragma unroll
                for (int r = 0; r < 4; r++) {
                    float mx = -3.0e38f;
#pragma unroll
                    for (int j = 0; j < 4; j++) {
                        float sv = sf[j][r] * SCL;
                        sf[j][r] = sv;
                        mx = fmaxf(mx, sv);
                    }
                    tmax[r] = mx;
                }
            }
#pragma unroll
            for (int r = 0; r < 4; r++) {
#pragma unroll
                for (int m = 1; m < 16; m <<= 1) tmax[r] = fmaxf(tmax[r], __shfl_xor(tmax[r], m));
            }
#pragma unroll
            for (int r = 0; r < 4; r++) {
                float mn = fmaxf(mrow[r], tmax[r]);
                float alpha = __builtin_amdgcn_exp2f(mrow[r] - mn);
                mrow[r] = mn;
                lrow[r] *= alpha;
#pragma unroll
                for (int jd = 0; jd < 4; jd++) Oa[jd][r] *= alpha;
            }
            float rsum[4] = {0.f, 0.f, 0.f, 0.f};
#pragma unroll
            for (int j = 0; j < 4; j++)
#pragma unroll
                for (int r = 0; r < 4; r++) {
                    float p = __builtin_amdgcn_exp2f(sf[j][r] - mrow[r]);
                    sf[j][r] = p;
                    rsum[r] += p;
                }
#pragma unroll
            for (int r = 0; r < 4; r++) {
#pragma unroll
                for (int m = 1; m < 16; m <<= 1) rsum[r] += __shfl_xor(rsum[r], m);
                lrow[r] += rsum[r];
            }

            // P -> LDS (wave-local rows, XOR-swizzled) -> A fragments
#pragma unroll
            for (int r = 0; r < 4; r++) {
                int qrow = wv * 16 + kg * 4 + r;
                int base = qrow * 64;
                int sw = (qrow & 7) << 3;
#pragma unroll
                for (int j = 0; j < 4; j++)
                    PL[(base + j * 16 + mr) ^ sw] = f2bf(sf[j][r]);
            }

            // O += P @ V
#pragma unroll
            for (int c = 0; c < 2; c++) {
                bf16x8 pa = *reinterpret_cast<const bf16x8*>(
                    &PL[(wv * 16 + mr) * 64 + ((4 * c + kg) ^ csw) * 8]);
#pragma unroll
                for (int jd = 0; jd < 4; jd++) {
                    int rv = jd * 16 + mr;
                    bf16x8 vb = *reinterpret_cast<const bf16x8*>(
                        &Vb[cur][rv * 64 + ((4 * c + kg) ^ csw) * 8]);
                    Oa[jd] = __builtin_amdgcn_mfma_f32_16x16x32_bf16(pa, vb, Oa[jd], 0, 0, 0);
                }
            }
            __syncthreads();  // staging drained; all waves done with buf[cur]
        }

        // epilogue: ctx = O / l
        float inv[4];
#pragma unroll
        for (int r = 0; r < 4; r++) inv[r] = 1.0f / lrow[r];
#pragma unroll
        for (int jd = 0; jd < 4; jd++)
#pragma unroll
            for (int r = 0; r < 4; r++) {
                int q = qbase + kg * 4 + r;
                ctx[(size_t)(b * TT + q) * N_EMBED + h * HD + jd * 16 + mr] =
                    f2bf(Oa[jd][r] * inv[r]);
            }
    }
}

// ---------------------------------------------------------------------------
extern "C" void kernel_launch(void* const* d_in, const int* in_sizes, int n_in,
                              void* d_out, int out_size, void* d_ws, size_t ws_size,
                              hipStream_t stream) {
    const float* x      = (const float*)d_in[0];
    const float* ln1_w  = (const float*)d_in[1];
    const float* ln1_b  = (const float*)d_in[2];
    const float* w_qkv  = (const float*)d_in[3];
    const float* b_qkv  = (const float*)d_in[4];
    const float* w_o    = (const float*)d_in[5];
    const float* b_o    = (const float*)d_in[6];
    const float* ln2_w  = (const float*)d_in[7];
    const float* ln2_b  = (const float*)d_in[8];
    const float* w_fc   = (const float*)d_in[9];
    const float* b_fc   = (const float*)d_in[10];
    const float* w_proj = (const float*)d_in[11];
    const float* b_proj = (const float*)d_in[12];
    float* out = (float*)d_out;

    char* ws = (char*)d_ws;
    size_t off = 0;
    auto alloc = [&](size_t bytes) -> void* {
        void* p = ws + off;
        off += (bytes + 255) & ~(size_t)255;
        return p;
    };
    unsigned short* wqkv_t  = (unsigned short*)alloc((size_t)3072 * 1024 * 2);
    unsigned short* wo_t    = (unsigned short*)alloc((size_t)1024 * 1024 * 2);
    unsigned short* wfc_t   = (unsigned short*)alloc((size_t)4096 * 1024 * 2);
    unsigned short* wproj_t = (unsigned short*)alloc((size_t)1024 * 4096 * 2);
    unsigned short* lnb     = (unsigned short*)alloc((size_t)NTOK * 1024 * 2);
    float*          x1      = (float*)alloc((size_t)NTOK * 1024 * 4);
    unsigned short* qkv     = (unsigned short*)alloc((size_t)NTOK * 3072 * 2);
    unsigned short* ctxb    = (unsigned short*)alloc((size_t)NTOK * 1024 * 2);
    unsigned short* hbuf    = qkv;                 // overlays qkv (dead after attn)
    unsigned short* vt      = (unsigned short*)x1; // overlays x1 (written after attn)

    dim3 tb32(32, 8);
    transpose_bf16_kernel<<<dim3(3072 / 32, 1024 / 32), tb32, 0, stream>>>(w_qkv, wqkv_t, 1024, 3072);
    transpose_bf16_kernel<<<dim3(1024 / 32, 1024 / 32), tb32, 0, stream>>>(w_o, wo_t, 1024, 1024);
    transpose_bf16_kernel<<<dim3(4096 / 32, 1024 / 32), tb32, 0, stream>>>(w_fc, wfc_t, 1024, 4096);
    transpose_bf16_kernel<<<dim3(1024 / 32, 4096 / 32), tb32, 0, stream>>>(w_proj, wproj_t, 4096, 1024);

    // ln1(x) -> lnb
    ln_kernel<<<NTOK, 256, 0, stream>>>(x, ln1_w, ln1_b, lnb);
    // qkv = lnb @ w_qkv + b_qkv
    gemm_kernel<0><<<(NTOK / 128) * (3072 / 128), 256, 0, stream>>>(
        lnb, wqkv_t, b_qkv, nullptr, nullptr, qkv, NTOK, 3072, 1024);
    // V transpose -> vt
    transpose_v_kernel<<<dim3(TT / 32, HD / 32, BB * N_HEAD), tb32, 0, stream>>>(qkv, vt);
    // attention -> ctx
    attn_kernel<<<1024, 256, 0, stream>>>(qkv, vt, ctxb);
    // x1 = ctx @ w_o + b_o + x   (x1 overwrites vt region — vt dead now)
    gemm_kernel<1><<<(NTOK / 128) * (1024 / 128), 256, 0, stream>>>(
        ctxb, wo_t, b_o, x, x1, nullptr, NTOK, 1024, 1024);
    // ln2(x1) -> lnb
    ln_kernel<<<NTOK, 256, 0, stream>>>(x1, ln2_w, ln2_b, lnb);
    // h = gelu(lnb @ w_fc + b_fc)
    gemm_kernel<2><<<(NTOK / 128) * (4096 / 128), 256, 0, stream>>>(
        lnb, wfc_t, b_fc, nullptr, nullptr, hbuf, NTOK, 4096, 1024);
    // out = h @ w_proj + b_proj + x1
    gemm_kernel<1><<<(NTOK / 128) * (1024 / 128), 256, 0, stream>>>(
        hbuf, wproj_t, b_proj, x1, out, nullptr, NTOK, 1024, 4096);
}